// Round 9
// baseline (18.720 us; speedup 1.0000x reference)
//
#include <hip/hip_runtime.h>
#include <hip/hip_bf16.h>
#include <cstdint>
#include <climits>

#define HW 112
#define NPIX (HW*HW)   // 12544
#define NB 2
#define NC 4
#define CHUNKS 14                  // chunks per (pair,dir); 8 rows each
#define HD_GRID (12*CHUNKS)        // 168

// ws layout:
//   +0:      packed masks  uint64_t[12 masks][112 rows][2 words]   (21504 B)
//   +21504:  g^2 planes    uint16_t[12 planes][12544]              (301056 B)
//   +322560: pdS[12] | +322608: pdC[12] | +322656: pdcnt[12]u | +322704: gcnt
//   (37 words zeroed by prep block 0 every launch - replay-safe, R8-proven)
// mask id = b*6 + m, m=0..2 -> A(j=m+1) (argmax==j), m=3..5 -> B(j=m-2) (label==1)

__global__ __launch_bounds__(128) void prep_kernel(
    const float* __restrict__ pred, const int* __restrict__ labels,
    unsigned long long* __restrict__ masks, unsigned short* __restrict__ gsqbuf,
    float* __restrict__ accum)
{
  int blk = blockIdx.x;
  int b = blk / HW, r = blk % HW;
  int tid = threadIdx.x;
  int lane = tid & 63, wave = tid >> 6;
  int c = tid;

  if (blk == 0 && tid < 37) accum[tid] = 0.f;   // pdS, pdC, pdcnt, gcnt := 0

  int cls = 255;
  if (c < HW) {
    const float* p0 = pred + ((size_t)(b*NC)*HW + r)*HW + c;
    float best = p0[0]; cls = 0;
    #pragma unroll
    for (int ch = 1; ch < NC; ch++) {
      float v = p0[(size_t)ch*NPIX];
      if (v > best) { best = v; cls = ch; }   // strict > : argmax tie-break
    }
  }

  __shared__ unsigned long long sm[6][2];
  #pragma unroll
  for (int m = 0; m < 3; m++) {
    bool p = (c < HW) && (cls == m + 1);
    unsigned long long bal = __ballot(p);
    if (lane == 0) sm[m][wave] = bal;
  }
  #pragma unroll
  for (int m = 0; m < 3; m++) {
    int lab = (c < HW) ? labels[((size_t)(b*NC + (m+1))*HW + r)*HW + c] : 0;
    bool p = (c < HW) && (lab == 1);
    unsigned long long bal = __ballot(p);
    if (lane == 0) sm[3 + m][wave] = bal;
  }
  __syncthreads();

  if (tid < 12) {
    int m = tid >> 1, w = tid & 1;
    masks[((size_t)(b*6 + m)*HW + r)*2 + w] = sm[m][w];
  }

  // phase 1: horizontal nearest-set-pixel distance, O(1)/pixel via clz/ffs
  for (int item = tid; item < 6*HW; item += 128) {
    int m = item / HW, cc = item % HW;
    unsigned long long lo = sm[m][0], hi = sm[m][1];
    int left, right;
    if (cc < 64) {
      unsigned long long wl = lo & ((2ull << cc) - 1);
      left = wl ? 63 - __clzll(wl) : -1000;
      unsigned long long wr = lo & ~((1ull << cc) - 1);
      right = wr ? __ffsll(wr) - 1 : (hi ? 64 + __ffsll(hi) - 1 : 1000);
    } else {
      int cl = cc - 64;
      unsigned long long wl = hi & ((2ull << cl) - 1);
      left = wl ? 64 + 63 - __clzll(wl) : (lo ? 63 - __clzll(lo) : -1000);
      unsigned long long wr = hi & ~((1ull << cl) - 1);
      right = wr ? 64 + __ffsll(wr) - 1 : 1000;
    }
    int gv = min(min(cc - left, right - cc), 255);  // 255 sentinel: empty row
    gsqbuf[(size_t)(b*6 + m)*NPIX + r*HW + cc] = (unsigned short)(gv*gv);
  }
}

__device__ __forceinline__ int g2row(const unsigned short* __restrict__ g2p, int row) {
  return (row >= 0 && row < HW) ? (int)g2p[(size_t)row*HW] : 0x7fff;
}

// 168 thin blocks (pd x 8-row chunk, 128 threads = columns). Early-exit d<=2
// window + rare exact tail (R7-proven). Completion: hierarchical atomics -
// per-pd accumulate (14 RMW/line, 12 lines in parallel) -> per-pd counter ->
// global counter -> last block finalizes inline (R5/R8-proven RMW read-back).
__global__ __launch_bounds__(128) void hd_kernel(
    const unsigned long long* __restrict__ masks,
    const unsigned short* __restrict__ gsqbuf,
    float* __restrict__ accum, float* __restrict__ out)
{
  float* pdS = accum;
  float* pdC = accum + 12;
  unsigned* pdcnt = (unsigned*)(accum + 24);
  unsigned* gcnt  = (unsigned*)(accum + 36);

  int blk = blockIdx.x;
  int pd = blk / CHUNKS, chunk = blk % CHUNKS;
  int b = pd / 6, k = pd % 6;
  // k<3: fwd for j=k+1 (src plane = B mask, target = A mask); k>=3 swapped
  int src = b*6 + (k + 3) % 6;
  int tid = threadIdx.x, lane = tid & 63, wv = tid >> 6;
  int c = tid;
  int rbase = chunk * 8;

  float sum = 0.f, cf = 0.f;
  if (c < HW) {
    const unsigned short* g2p = gsqbuf + (size_t)src*NPIX + c;
    int vm2 = g2row(g2p, rbase - 2), vm1 = g2row(g2p, rbase - 1);
    int v0  = g2row(g2p, rbase),     vp1 = g2row(g2p, rbase + 1);
    int vp2 = g2row(g2p, rbase + 2);
    #pragma unroll 8
    for (int i = 0; i < 8; i++) {
      int r = rbase + i;
      int best = v0;
      best = min(best, 1 + min(vm1, vp1));
      best = min(best, 4 + min(vm2, vp2));
      if (best > 9) {                         // rare exact tail
        for (int d = 3; d < HW; d++) {
          int dd = d*d;
          if (dd >= best) break;
          int ru = r - d, rd = r + d;
          if (ru >= 0)  best = min(best, dd + (int)g2p[(size_t)ru*HW]);
          if (rd < HW)  best = min(best, dd + (int)g2p[(size_t)rd*HW]);
        }
      }
      unsigned long long wm = masks[((size_t)pd*HW + r)*2 + (c >> 6)];
      if ((wm >> (c & 63)) & 1ull) { sum += sqrtf((float)best); cf += 1.f; }
      vm2 = vm1; vm1 = v0; v0 = vp1; vp1 = vp2; vp2 = g2row(g2p, r + 3);
    }
  }

  #pragma unroll
  for (int off = 32; off; off >>= 1) {
    sum += __shfl_down(sum, off, 64);
    cf  += __shfl_down(cf, off, 64);
  }
  __shared__ float red[4];
  __shared__ int doFin;
  if (lane == 0) { red[wv*2] = sum; red[wv*2 + 1] = cf; }
  __syncthreads();
  if (tid == 0) {
    doFin = 0;
    atomicAdd(&pdS[pd], red[0] + red[2]);
    atomicAdd(&pdC[pd], red[1] + red[3]);
    __threadfence();
    unsigned pdold = atomicAdd(&pdcnt[pd], 1u);
    if (pdold == CHUNKS - 1) {                // pd complete
      unsigned gold = atomicAdd(gcnt, 1u);
      if (gold == 11) doFin = 1;              // all 12 pds complete
    }
  }
  __syncthreads();

  if (doFin) {
    __shared__ float sacc[24];
    if (tid < 12)       sacc[tid]      = atomicAdd(&pdS[tid], 0.0f);   // coherent RMW read
    else if (tid < 24)  sacc[tid]      = atomicAdd(&pdC[tid - 12], 0.0f);
    __syncthreads();
    if (tid == 0) {
      float mhd[6], fhd[6], rhd[6];
      for (int i = 0; i < 6; i++) { mhd[i] = 0.f; fhd[i] = 0.f; rhd[i] = 0.f; }
      for (int bb = 0; bb < 2; bb++)
        for (int j = 1; j < 4; j++) {
          int pf = bb*6 + (j - 1);
          int pr = bb*6 + 3 + (j - 1);
          float fwd = sacc[pf] / sacc[12 + pf];
          float rev = sacc[pr] / sacc[12 + pr];
          fhd[j] += fwd; rhd[j] += rev; mhd[j] += fmaxf(fwd, rev);
        }
      float* arrs[3] = { mhd, fhd, rhd };
      for (int a = 0; a < 3; a++) {
        float* x = arrs[a];
        for (int i = 0; i < 4; i++) x[i] *= 0.5f;          // /N
        x[4] = (x[0] + x[1] + x[2] + x[3]) * 0.25f;        // mean(x[:C])
        x[5] = (x[1] + x[2] + x[3]) * (1.f / 3.f);         // mean(x[1:C])
        for (int i = 0; i < 6; i++) out[a*6 + i] = x[i];
      }
    }
  }
}

extern "C" void kernel_launch(void* const* d_in, const int* in_sizes, int n_in,
                              void* d_out, int out_size, void* d_ws, size_t ws_size,
                              hipStream_t stream) {
  const float* pred = (const float*)d_in[0];
  const int* labels = (const int*)d_in[1];
  float* out = (float*)d_out;

  unsigned long long* masks = (unsigned long long*)d_ws;
  unsigned short* gsqbuf = (unsigned short*)((char*)d_ws + 21504);
  float* accum = (float*)((char*)d_ws + 322560);

  prep_kernel<<<NB*HW, 128, 0, stream>>>(pred, labels, masks, gsqbuf, accum);
  hd_kernel<<<HD_GRID, 128, 0, stream>>>(masks, gsqbuf, accum, out);
}

// Round 10
// 15.895 us; speedup vs baseline: 1.1777x; 1.1777x over previous
//
#include <hip/hip_runtime.h>
#include <hip/hip_bf16.h>
#include <cstdint>
#include <climits>

#define HW 112
#define NPIX (HW*HW)   // 12544
#define NB 2
#define NC 4
#define CHUNKS 14                  // chunks per (pair,dir); 8 rows each
#define HD_WORK (12*CHUNKS)        // 168 worker blocks; block 168 = finalizer

// ws layout:
//   +0:      packed masks  uint64_t[12 masks][112 rows][2 words]   (21504 B)
//   +21504:  g^2 planes    uint16_t[12 planes][12544]              (301056 B)
//   +322560: slots u64[168] — payload (count<<32 | f32bits(sum)) per worker.
//            Invalidated (count=0xFFFFFFFF) by prep block 0 each launch; the
//            prep->hd graph edge orders the invalidation before all hd blocks.
//            No fences: the payload IS the completion flag (count<=12544).
// mask id = b*6 + m, m=0..2 -> A(j=m+1) (argmax==j), m=3..5 -> B(j=m-2) (label==1)

__global__ __launch_bounds__(128) void prep_kernel(
    const float* __restrict__ pred, const int* __restrict__ labels,
    unsigned long long* __restrict__ masks, unsigned short* __restrict__ gsqbuf,
    unsigned long long* __restrict__ slots)
{
  int blk = blockIdx.x;
  int b = blk / HW, r = blk % HW;
  int tid = threadIdx.x;
  int lane = tid & 63, wave = tid >> 6;
  int c = tid;

  if (blk == 0) {            // invalidate payload slots (plain stores; graph
    for (int i = tid; i < HD_WORK; i += 128)   // edge orders before hd)
      slots[i] = 0xFFFFFFFFFFFFFFFFull;
  }

  int cls = 255;
  if (c < HW) {
    const float* p0 = pred + ((size_t)(b*NC)*HW + r)*HW + c;
    float best = p0[0]; cls = 0;
    #pragma unroll
    for (int ch = 1; ch < NC; ch++) {
      float v = p0[(size_t)ch*NPIX];
      if (v > best) { best = v; cls = ch; }   // strict > : argmax tie-break
    }
  }

  __shared__ unsigned long long sm[6][2];
  #pragma unroll
  for (int m = 0; m < 3; m++) {
    bool p = (c < HW) && (cls == m + 1);
    unsigned long long bal = __ballot(p);
    if (lane == 0) sm[m][wave] = bal;
  }
  #pragma unroll
  for (int m = 0; m < 3; m++) {
    int lab = (c < HW) ? labels[((size_t)(b*NC + (m+1))*HW + r)*HW + c] : 0;
    bool p = (c < HW) && (lab == 1);
    unsigned long long bal = __ballot(p);
    if (lane == 0) sm[3 + m][wave] = bal;
  }
  __syncthreads();

  if (tid < 12) {
    int m = tid >> 1, w = tid & 1;
    masks[((size_t)(b*6 + m)*HW + r)*2 + w] = sm[m][w];
  }

  // phase 1: horizontal nearest-set-pixel distance, O(1)/pixel via clz/ffs
  for (int item = tid; item < 6*HW; item += 128) {
    int m = item / HW, cc = item % HW;
    unsigned long long lo = sm[m][0], hi = sm[m][1];
    int left, right;
    if (cc < 64) {
      unsigned long long wl = lo & ((2ull << cc) - 1);
      left = wl ? 63 - __clzll(wl) : -1000;
      unsigned long long wr = lo & ~((1ull << cc) - 1);
      right = wr ? __ffsll(wr) - 1 : (hi ? 64 + __ffsll(hi) - 1 : 1000);
    } else {
      int cl = cc - 64;
      unsigned long long wl = hi & ((2ull << cl) - 1);
      left = wl ? 64 + 63 - __clzll(wl) : (lo ? 63 - __clzll(lo) : -1000);
      unsigned long long wr = hi & ~((1ull << cl) - 1);
      right = wr ? 64 + __ffsll(wr) - 1 : 1000;
    }
    int gv = min(min(cc - left, right - cc), 255);  // 255 sentinel: empty row
    gsqbuf[(size_t)(b*6 + m)*NPIX + r*HW + cc] = (unsigned short)(gv*gv);
  }
}

__device__ __forceinline__ int g2row(const unsigned short* __restrict__ g2p, int row) {
  return (row >= 0 && row < HW) ? (int)g2p[(size_t)row*HW] : 0x7fff;
}

// Blocks 0..167: thin workers (pd x 8-row chunk, 128 threads = columns),
// early-exit d<=2 window + rare exact tail (R7-proven). Each ends with ONE
// fence-free 64-bit atomicExch payload publish.
// Block 168: spins on the 168 payload slots (valid iff count<=12544), then
// reduces and writes the 18 outputs. Replay-stale payloads are bit-identical
// (deterministic), so early reads remain correct (R5-proven argument).
__global__ __launch_bounds__(128) void hd_kernel(
    const unsigned long long* __restrict__ masks,
    const unsigned short* __restrict__ gsqbuf,
    unsigned long long* __restrict__ slots, float* __restrict__ out)
{
  int blk = blockIdx.x;
  int tid = threadIdx.x, lane = tid & 63, wv = tid >> 6;

  if (blk < HD_WORK) {
    int pd = blk / CHUNKS, chunk = blk % CHUNKS;
    int b = pd / 6, k = pd % 6;
    // k<3: fwd for j=k+1 (src plane = B mask, target = A mask); k>=3 swapped
    int src = b*6 + (k + 3) % 6;
    int c = tid;
    int rbase = chunk * 8;

    float sum = 0.f, cf = 0.f;
    if (c < HW) {
      const unsigned short* g2p = gsqbuf + (size_t)src*NPIX + c;
      int vm2 = g2row(g2p, rbase - 2), vm1 = g2row(g2p, rbase - 1);
      int v0  = g2row(g2p, rbase),     vp1 = g2row(g2p, rbase + 1);
      int vp2 = g2row(g2p, rbase + 2);
      #pragma unroll 8
      for (int i = 0; i < 8; i++) {
        int r = rbase + i;
        int best = v0;
        best = min(best, 1 + min(vm1, vp1));
        best = min(best, 4 + min(vm2, vp2));
        if (best > 9) {                         // rare exact tail
          for (int d = 3; d < HW; d++) {
            int dd = d*d;
            if (dd >= best) break;
            int ru = r - d, rd = r + d;
            if (ru >= 0)  best = min(best, dd + (int)g2p[(size_t)ru*HW]);
            if (rd < HW)  best = min(best, dd + (int)g2p[(size_t)rd*HW]);
          }
        }
        unsigned long long wm = masks[((size_t)pd*HW + r)*2 + (c >> 6)];
        if ((wm >> (c & 63)) & 1ull) { sum += sqrtf((float)best); cf += 1.f; }
        vm2 = vm1; vm1 = v0; v0 = vp1; vp1 = vp2; vp2 = g2row(g2p, r + 3);
      }
    }

    #pragma unroll
    for (int off = 32; off; off >>= 1) {
      sum += __shfl_down(sum, off, 64);
      cf  += __shfl_down(cf, off, 64);
    }
    __shared__ float red[4];
    if (lane == 0) { red[wv*2] = sum; red[wv*2 + 1] = cf; }
    __syncthreads();
    if (tid == 0) {
      float S = red[0] + red[2];
      unsigned cnt = (unsigned)(red[1] + red[3]);   // exact small int
      unsigned long long pay = ((unsigned long long)cnt << 32)
                             | (unsigned long long)__float_as_uint(S);
      atomicExch(&slots[blk], pay);                 // fence-free publish
    }
  } else {
    // ---- finalizer block ----
    __shared__ float fs[HD_WORK], fc[HD_WORK], sacc[24];
    for (int i = tid; i < HD_WORK; i += 128) {
      unsigned long long v = atomicAdd((unsigned long long*)&slots[i], 0ull);
      while ((unsigned)(v >> 32) > 12544u) {        // not yet published
        __builtin_amdgcn_s_sleep(2);
        v = atomicAdd((unsigned long long*)&slots[i], 0ull);
      }
      fs[i] = __uint_as_float((unsigned)v);
      fc[i] = (float)(unsigned)(v >> 32);
    }
    __syncthreads();
    if (tid < 12) {
      float s = 0.f, cc = 0.f;
      for (int i = 0; i < CHUNKS; i++) { s += fs[tid*CHUNKS + i]; cc += fc[tid*CHUNKS + i]; }
      sacc[tid] = s; sacc[12 + tid] = cc;
    }
    __syncthreads();
    if (tid == 0) {
      float mhd[6], fhd[6], rhd[6];
      for (int i = 0; i < 6; i++) { mhd[i] = 0.f; fhd[i] = 0.f; rhd[i] = 0.f; }
      for (int bb = 0; bb < 2; bb++)
        for (int j = 1; j < 4; j++) {
          int pf = bb*6 + (j - 1);
          int pr = bb*6 + 3 + (j - 1);
          float fwd = sacc[pf] / sacc[12 + pf];
          float rev = sacc[pr] / sacc[12 + pr];
          fhd[j] += fwd; rhd[j] += rev; mhd[j] += fmaxf(fwd, rev);
        }
      float* arrs[3] = { mhd, fhd, rhd };
      for (int a = 0; a < 3; a++) {
        float* x = arrs[a];
        for (int i = 0; i < 4; i++) x[i] *= 0.5f;          // /N
        x[4] = (x[0] + x[1] + x[2] + x[3]) * 0.25f;        // mean(x[:C])
        x[5] = (x[1] + x[2] + x[3]) * (1.f / 3.f);         // mean(x[1:C])
        for (int i = 0; i < 6; i++) out[a*6 + i] = x[i];
      }
    }
  }
}

extern "C" void kernel_launch(void* const* d_in, const int* in_sizes, int n_in,
                              void* d_out, int out_size, void* d_ws, size_t ws_size,
                              hipStream_t stream) {
  const float* pred = (const float*)d_in[0];
  const int* labels = (const int*)d_in[1];
  float* out = (float*)d_out;

  unsigned long long* masks = (unsigned long long*)d_ws;
  unsigned short* gsqbuf = (unsigned short*)((char*)d_ws + 21504);
  unsigned long long* slots = (unsigned long long*)((char*)d_ws + 322560);

  prep_kernel<<<NB*HW, 128, 0, stream>>>(pred, labels, masks, gsqbuf, slots);
  hd_kernel<<<HD_WORK + 1, 128, 0, stream>>>(masks, gsqbuf, slots, out);
}